// Round 18
// baseline (240.000 us; speedup 1.0000x reference)
//
#include <hip/hip_runtime.h>
#include <math.h>

// Problem constants
#define NN       16384
#define IN_DIM   64
#define CC       4
#define NMAT     (NN * CC)

// Taylor coefficients 1/k!
#define C0 1.0f
#define C1 1.0f
#define C2 0.5f
#define C3 0.16666666666666666f
#define C4 0.041666666666666664f
#define C5 0.008333333333333333f
#define C6 0.001388888888888889f
#define C7 1.984126984126984e-4f
#define C8 2.48015873015873e-5f

typedef __attribute__((ext_vector_type(8))) short bf16x8;   // 8 bf16 = 4 VGPR
typedef __attribute__((ext_vector_type(4))) float f32x4;    // C/D frag

#define MFMA16(A, B, C) __builtin_amdgcn_mfma_f32_16x16x32_bf16((A), (B), (C), 0, 0, 0)

// Two 48B-column-stride regions per matrix, planes at +800B steps:
//   RC @0    : colmaj A, then T (B-operand side of every cmul)
//   RR @3200 : colmaj conj(Z) during Horner; rowmaj(T) in squarings (A-op side)
// Planes: XH@0, YH@800, XL@1600, YL@2400 (LOD=1600).
#define PXH  0
#define PYH  800
#define LOD  1600
#define RC   0
#define RR   3200
#define MATB 6400
#define WPB  4               // matrices (waves) per 256-thread block

__device__ __forceinline__ unsigned fbits(float x) {
    return __builtin_bit_cast(unsigned, x);
}
__device__ __forceinline__ float hif(float x) {
    return __builtin_bit_cast(float, fbits(x) & 0xFFFF0000u);
}
// pack bf16(a) | bf16(b)<<16 as ONE v_perm_b32
__device__ __forceinline__ unsigned pkp(float a, float b) {
    return __builtin_amdgcn_perm(fbits(b), fbits(a), 0x07060302u);
}

// ---------------------------------------------------------------------------
// Phase 1: B[n,c,i,j] = sum_k dX[n,k] * (Ar + i*Ai)[k,c,i,j]  -> ws
// ---------------------------------------------------------------------------
__global__ __launch_bounds__(256)
void ax_kernel(const float* __restrict__ dX, const float* __restrict__ Ar,
               const float* __restrict__ Ai, float* __restrict__ ws)
{
    const int t  = threadIdx.x;
    const int nb = blockIdx.x * 8;
    const int c  = t >> 6;
    const int i  = (t >> 2) & 15;
    const int j0 = (t & 3) * 4;

    float accre[8][4], accim[8][4];
#pragma unroll
    for (int nn_ = 0; nn_ < 8; ++nn_)
#pragma unroll
        for (int jj = 0; jj < 4; ++jj) { accre[nn_][jj] = 0.f; accim[nn_][jj] = 0.f; }

#pragma unroll 2
    for (int k = 0; k < IN_DIM; ++k) {
        const int base = (k * CC + c) * 256 + i * 16 + j0;
        const float4 ar = *reinterpret_cast<const float4*>(Ar + base);
        const float4 ai = *reinterpret_cast<const float4*>(Ai + base);
#pragma unroll
        for (int nn_ = 0; nn_ < 8; ++nn_) {
            const float dxv = dX[(nb + nn_) * IN_DIM + k];
#pragma unroll
            for (int jj = 0; jj < 4; ++jj) {
                accre[nn_][jj] = fmaf(dxv, (&ar.x)[jj], accre[nn_][jj]);
                accim[nn_][jj] = fmaf(dxv, (&ai.x)[jj], accim[nn_][jj]);
            }
        }
    }
#pragma unroll
    for (int nn_ = 0; nn_ < 8; ++nn_) {
        const int m = (nb + nn_) * CC + c;
        float* o = ws + (size_t)m * 512 + (i * 16 + j0) * 2;
        reinterpret_cast<float4*>(o)[0] =
            make_float4(accre[nn_][0], accim[nn_][0], accre[nn_][1], accim[nn_][1]);
        reinterpret_cast<float4*>(o)[1] =
            make_float4(accre[nn_][2], accim[nn_][2], accre[nn_][3], accim[nn_][3]);
    }
}

// ---------------------------------------------------------------------------
// Phase 2 (MFMA): one matrix per wave. Algorithm frozen at round-14/17 state
// (passed, absmax 0.0039). Round-18 micro-levers: (1) two-chain mfma
// accumulation (depth 3 -> 2 + f32x4 add), (2) s_setprio(1) around mfma
// clusters (barrier-free waves at divergent phases -> T5 regime), (3) final
// squaring peeled out of the loop.
// ---------------------------------------------------------------------------
__global__ __launch_bounds__(256)
void expm_mfma_kernel(const float* __restrict__ dX, const float* __restrict__ Ar,
                      const float* __restrict__ Ai, const float* __restrict__ ws,
                      float* __restrict__ out, const int use_ws, const int real_only)
{
    __shared__ __align__(16) unsigned char ldsraw[WPB * MATB];

    const int t = threadIdx.x;
    const int w = t >> 6;
    const int l = t & 63;
    unsigned char* const L = ldsraw + w * MATB;

    const int m  = blockIdx.x * WPB + w;
    const int n  = m >> 2;
    const int cc = m & 3;

    const int c  = l & 15;         // owned column (C/D); frag row/col
    const int g  = l >> 4;
    const int gh = g & 1;
    const bool gs = (g >= 2);      // k>=16 half -> Y-plane side
    const int colent = c * 48 + gh * 16;
    const int o1 = (gs ? PYH : PXH) + colent;   // B1 / plain-A hi offset
    const int o2 = (gs ? PXH : PYH) + colent;   // B2 hi offset
    const int wc = c * 48 + g * 8;              // colmaj write offset

    // ---- precomputed DS base pointers (all further offsets are imm consts)
    unsigned char* const pWc  = L + RC + wc;                    // colmaj write, RC
    unsigned char* const pWcR = L + RR + wc;                    // colmaj write, RR
    unsigned char* const pWr0 = L + RR + (4 * g) * 48 + c * 2;  // rowmaj scatter base
    const unsigned char* const pRd1 = L + RC + o1;              // B1-style read (RC)
    const unsigned char* const pRd2 = L + RC + o2;              // B2-style read (RC)
    const unsigned char* const pRdA = L + RR + o1;              // plain A-read (RR)

    const short ns = (short)0x8000;
    const bf16x8 negall = {ns, ns, ns, ns, ns, ns, ns, ns};
    const bf16x8 zero8  = {0, 0, 0, 0, 0, 0, 0, 0};
    const bf16x8 mB1 = gs ? negall : zero8;   // B1 = [X ; -Y]
    const bf16x8 mA1 = gs ? zero8 : negall;   // A-op of skew-Herm A: [-X | +Y]
    const f32x4 fz = {0.f, 0.f, 0.f, 0.f};

    f32x4 dqv;
#pragma unroll
    for (int q = 0; q < 4; ++q) dqv[q] = ((4 * g + q) == c) ? 1.f : 0.f;

    // ---- load AX (C/D ownership) + transposed elements; skew-project
    f32x4 aRv, aIv;
    if (use_ws) {
        const float* gp = ws + (size_t)m * 512;
#pragma unroll
        for (int q = 0; q < 4; ++q) {
            const int r = 4 * g + q;
            const float2 v = *reinterpret_cast<const float2*>(gp + (r * 16 + c) * 2);
            const float2 u = *reinterpret_cast<const float2*>(gp + (c * 16 + r) * 2);
            aRv[q] = 0.5f * (v.x - u.x);
            aIv[q] = 0.5f * (v.y + u.y);
        }
    } else {
        float bRe[4] = {0,0,0,0}, bIm[4] = {0,0,0,0}, uRe[4] = {0,0,0,0}, uIm[4] = {0,0,0,0};
        for (int k = 0; k < IN_DIM; ++k) {
            const float dxv = dX[n * IN_DIM + k];
            const int base = (k * CC + cc) * 256;
#pragma unroll
            for (int q = 0; q < 4; ++q) {
                const int r = 4 * g + q;
                bRe[q] = fmaf(dxv, Ar[base + r * 16 + c], bRe[q]);
                bIm[q] = fmaf(dxv, Ai[base + r * 16 + c], bIm[q]);
                uRe[q] = fmaf(dxv, Ar[base + c * 16 + r], uRe[q]);
                uIm[q] = fmaf(dxv, Ai[base + c * 16 + r], uIm[q]);
            }
        }
#pragma unroll
        for (int q = 0; q < 4; ++q) {
            aRv[q] = 0.5f * (bRe[q] - uRe[q]);
            aIv[q] = 0.5f * (bIm[q] + uIm[q]);
        }
    }

    // ---- helpers (all DS via fixed pointers + imm offsets) -------------------
    auto wcolV = [&](unsigned char* Rb, const f32x4 vR, const f32x4 vI) {
        uint2 xh, yh, xl, yl;
        xh.x = pkp(vR[0], vR[1]); xh.y = pkp(vR[2], vR[3]);
        yh.x = pkp(vI[0], vI[1]); yh.y = pkp(vI[2], vI[3]);
        const float r0 = vR[0] - hif(vR[0]), r1 = vR[1] - hif(vR[1]);
        const float r2 = vR[2] - hif(vR[2]), r3 = vR[3] - hif(vR[3]);
        const float i0 = vI[0] - hif(vI[0]), i1 = vI[1] - hif(vI[1]);
        const float i2 = vI[2] - hif(vI[2]), i3 = vI[3] - hif(vI[3]);
        xl.x = pkp(r0, r1); xl.y = pkp(r2, r3);
        yl.x = pkp(i0, i1); yl.y = pkp(i2, i3);
        *reinterpret_cast<uint2*>(Rb + PXH)       = xh;
        *reinterpret_cast<uint2*>(Rb + PYH)       = yh;
        *reinterpret_cast<uint2*>(Rb + PXH + LOD) = xl;
        *reinterpret_cast<uint2*>(Rb + PYH + LOD) = yl;
    };
    auto wrowV = [&](const f32x4 vR, const f32x4 vI) {
#pragma unroll
        for (int q = 0; q < 4; ++q) {
            unsigned char* p = pWr0 + q * 48;
            *reinterpret_cast<unsigned short*>(p + PXH) =
                (unsigned short)(fbits(vR[q]) >> 16);
            *reinterpret_cast<unsigned short*>(p + PYH) =
                (unsigned short)(fbits(vI[q]) >> 16);
            const float lr = vR[q] - hif(vR[q]);
            const float li = vI[q] - hif(vI[q]);
            *reinterpret_cast<unsigned short*>(p + PXH + LOD) =
                (unsigned short)(fbits(lr) >> 16);
            *reinterpret_cast<unsigned short*>(p + PYH + LOD) =
                (unsigned short)(fbits(li) >> 16);
        }
    };
    // acc += (A-frags) * (matrix colmaj in RC). Two independent mfma chains
    // per component (depth <=2) + one vector add; setprio around the cluster.
    auto cmulV = [&](const bf16x8 Ah, const bf16x8 Al,
                     f32x4& re, f32x4& im, bool doIm) {
        const bf16x8 b1h = *reinterpret_cast<const bf16x8*>(pRd1) ^ mB1;
        const bf16x8 b1l = *reinterpret_cast<const bf16x8*>(pRd1 + LOD) ^ mB1;
        __builtin_amdgcn_s_setprio(1);
        f32x4 reA = MFMA16(Ah, b1h, re);       // chain A: init + 1
        f32x4 reB = MFMA16(Ah, b1l, fz);       // chain B: 2 deep
        reB = MFMA16(Al, b1h, reB);
        if (doIm) {
            const bf16x8 b2h = *reinterpret_cast<const bf16x8*>(pRd2);
            const bf16x8 b2l = *reinterpret_cast<const bf16x8*>(pRd2 + LOD);
            f32x4 imA = MFMA16(Ah, b2h, im);
            f32x4 imB = MFMA16(Ah, b2l, fz);
            imB = MFMA16(Al, b2h, imB);
            __builtin_amdgcn_s_setprio(0);
            im = imA + imB;
        } else {
            __builtin_amdgcn_s_setprio(0);
        }
        re = reA + reB;
    };

    // ---- unscaled A -> RC colmaj; Z0 = A*A (A-op = masked read of colmaj(A))
    wcolV(pWc, aRv, aIv);
    {
        const bf16x8 fh = *reinterpret_cast<const bf16x8*>(pRd1) ^ mA1;
        const bf16x8 fl = *reinterpret_cast<const bf16x8*>(pRd1 + LOD) ^ mA1;
        f32x4 zr4 = fz, zi4 = fz;
        cmulV(fh, fl, zr4, zi4, true);

        // ---- spectral s: ||A||_2^2 = ||Z0||_2 <= ||Z0||_1
        float colsum = 0.f;
#pragma unroll
        for (int q = 0; q < 4; ++q)
            colsum += sqrtf(zr4[q] * zr4[q] + zi4[q] * zi4[q]);
        colsum += __shfl_xor(colsum, 16);
        colsum += __shfl_xor(colsum, 32);
        float mx = colsum;
        mx = fmaxf(mx, __shfl_xor(mx, 1));
        mx = fmaxf(mx, __shfl_xor(mx, 2));
        mx = fmaxf(mx, __shfl_xor(mx, 4));
        mx = fmaxf(mx, __shfl_xor(mx, 8));

        int s_ = 0;
        if (mx > 1.f) s_ = (int)ceilf(0.5f * log2f(mx));
        if (s_ < 0) s_ = 0;
        if (s_ > 16) s_ = 16;
        const float sc1 = exp2f((float)(-s_));
        const float sc2 = sc1 * sc1;

        f32x4 zrv, ziv, nzv;
#pragma unroll
        for (int q = 0; q < 4; ++q) {
            aRv[q] *= sc1; aIv[q] *= sc1;
            zrv[q] = zr4[q] * sc2; ziv[q] = zi4[q] * sc2;
            nzv[q] = -ziv[q];
        }

        // ---- conj(Z) colmaj -> RR (== rowmaj(Z)); plain A-read presents Z
        wcolV(pWcR, zrv, nzv);
        const bf16x8 zfh = *reinterpret_cast<const bf16x8*>(pRdA);
        const bf16x8 zfl = *reinterpret_cast<const bf16x8*>(pRdA + LOD);

        // ---- seeds: T = C8 Z + C7 A + C6 I
        f32x4 tRv, tIv;
#pragma unroll
        for (int q = 0; q < 4; ++q) {
            tRv[q] = C8 * zrv[q] + C7 * aRv[q] + C6 * dqv[q];
            tIv[q] = C8 * ziv[q] + C7 * aIv[q];
        }

        // ---- 3 Horner steps: T <- Z*T + (eI + oA)
        const float cE[3] = {C4, C2, C0};
        const float cO[3] = {C5, C3, C1};
#pragma unroll
        for (int h = 0; h < 3; ++h) {
            wcolV(pWc, tRv, tIv);
            f32x4 ar, ai;
#pragma unroll
            for (int q = 0; q < 4; ++q) {
                ar[q] = cO[h] * aRv[q] + cE[h] * dqv[q];
                ai[q] = cO[h] * aIv[q];
            }
            cmulV(zfh, zfl, ar, ai, true);
            tRv = ar; tIv = ai;
        }

        // ---- (s-1) full squarings, then one peeled final squaring
#pragma unroll 1
        for (int it = 0; it < s_ - 1; ++it) {
            wcolV(pWc, tRv, tIv);
            wrowV(tRv, tIv);
            const bf16x8 afh = *reinterpret_cast<const bf16x8*>(pRdA);
            const bf16x8 afl = *reinterpret_cast<const bf16x8*>(pRdA + LOD);
            f32x4 r = fz, i4 = fz;
            cmulV(afh, afl, r, i4, true);
            tRv = r; tIv = i4;
        }
        if (s_ > 0) {
            wcolV(pWc, tRv, tIv);
            wrowV(tRv, tIv);
            const bf16x8 afh = *reinterpret_cast<const bf16x8*>(pRdA);
            const bf16x8 afl = *reinterpret_cast<const bf16x8*>(pRdA + LOD);
            f32x4 r = fz, i4 = fz;
            cmulV(afh, afl, r, i4, !real_only);
            tRv = r;
            if (!real_only) tIv = i4;
        }

        // ---- write result
        if (real_only) {
            float* po = out + (size_t)m * 256;
#pragma unroll
            for (int q = 0; q < 4; ++q)
                po[(4 * g + q) * 16 + c] = tRv[q];
        } else {
            float* po = out + (size_t)m * 512;
#pragma unroll
            for (int q = 0; q < 4; ++q)
                *reinterpret_cast<float2*>(po + ((4 * g + q) * 16 + c) * 2) =
                    make_float2(tRv[q], tIv[q]);
        }
    }
}

// ---------------------------------------------------------------------------
extern "C" void kernel_launch(void* const* d_in, const int* in_sizes, int n_in,
                              void* d_out, int out_size, void* d_ws, size_t ws_size,
                              hipStream_t stream)
{
    const float* dX = (const float*)d_in[0];
    const float* Ar = (const float*)d_in[1];
    const float* Ai = (const float*)d_in[2];
    float* out = (float*)d_out;
    float* ws  = (float*)d_ws;

    const int real_only = (out_size < NMAT * 512) ? 1 : 0;
    const size_t need = (size_t)NMAT * 512 * sizeof(float);
    const int use_ws = (ws_size >= need) ? 1 : 0;

    if (use_ws)
        hipLaunchKernelGGL(ax_kernel, dim3(NN / 8), dim3(256), 0, stream, dX, Ar, Ai, ws);
    hipLaunchKernelGGL(expm_mfma_kernel, dim3(NMAT / WPB), dim3(256), 0, stream,
                       dX, Ar, Ai, ws, out, use_ws, real_only);
}

// Round 19
// 223.666 us; speedup vs baseline: 1.0730x; 1.0730x over previous
//
#include <hip/hip_runtime.h>
#include <math.h>

// Problem constants
#define NN       16384
#define IN_DIM   64
#define CC       4
#define NMAT     (NN * CC)

// Taylor coefficients 1/k!
#define C0 1.0f
#define C1 1.0f
#define C2 0.5f
#define C3 0.16666666666666666f
#define C4 0.041666666666666664f
#define C5 0.008333333333333333f
#define C6 0.001388888888888889f
#define C7 1.984126984126984e-4f
#define C8 2.48015873015873e-5f

typedef __attribute__((ext_vector_type(8))) short bf16x8;   // 8 bf16 = 4 VGPR
typedef __attribute__((ext_vector_type(4))) float f32x4;    // C/D frag

#define MFMA16(A, B, C) __builtin_amdgcn_mfma_f32_16x16x32_bf16((A), (B), (C), 0, 0, 0)

// Two 48B-column-stride regions per matrix, planes at +800B steps:
//   RC @0    : colmaj A, then T (B-operand side of every cmul)
//   RR @3200 : colmaj conj(Z) during Horner; rowmaj(T) in squarings (A-op side)
// Planes: XH@0, YH@800, XL@1600, YL@2400 (LOD=1600).
#define PXH  0
#define PYH  800
#define LOD  1600
#define RC   0
#define RR   3200
#define MATB 6400
#define WPB  4               // matrices (waves) per 256-thread block

__device__ __forceinline__ unsigned fbits(float x) {
    return __builtin_bit_cast(unsigned, x);
}
__device__ __forceinline__ float hif(float x) {
    return __builtin_bit_cast(float, fbits(x) & 0xFFFF0000u);
}
// pack bf16(a) | bf16(b)<<16 as ONE v_perm_b32
__device__ __forceinline__ unsigned pkp(float a, float b) {
    return __builtin_amdgcn_perm(fbits(b), fbits(a), 0x07060302u);
}

// ---------------------------------------------------------------------------
// Phase 1: B[n,c,i,j] = sum_k dX[n,k] * (Ar + i*Ai)[k,c,i,j]  -> ws
// ---------------------------------------------------------------------------
__global__ __launch_bounds__(256)
void ax_kernel(const float* __restrict__ dX, const float* __restrict__ Ar,
               const float* __restrict__ Ai, float* __restrict__ ws)
{
    const int t  = threadIdx.x;
    const int nb = blockIdx.x * 8;
    const int c  = t >> 6;
    const int i  = (t >> 2) & 15;
    const int j0 = (t & 3) * 4;

    float accre[8][4], accim[8][4];
#pragma unroll
    for (int nn_ = 0; nn_ < 8; ++nn_)
#pragma unroll
        for (int jj = 0; jj < 4; ++jj) { accre[nn_][jj] = 0.f; accim[nn_][jj] = 0.f; }

#pragma unroll 2
    for (int k = 0; k < IN_DIM; ++k) {
        const int base = (k * CC + c) * 256 + i * 16 + j0;
        const float4 ar = *reinterpret_cast<const float4*>(Ar + base);
        const float4 ai = *reinterpret_cast<const float4*>(Ai + base);
#pragma unroll
        for (int nn_ = 0; nn_ < 8; ++nn_) {
            const float dxv = dX[(nb + nn_) * IN_DIM + k];
#pragma unroll
            for (int jj = 0; jj < 4; ++jj) {
                accre[nn_][jj] = fmaf(dxv, (&ar.x)[jj], accre[nn_][jj]);
                accim[nn_][jj] = fmaf(dxv, (&ai.x)[jj], accim[nn_][jj]);
            }
        }
    }
#pragma unroll
    for (int nn_ = 0; nn_ < 8; ++nn_) {
        const int m = (nb + nn_) * CC + c;
        float* o = ws + (size_t)m * 512 + (i * 16 + j0) * 2;
        reinterpret_cast<float4*>(o)[0] =
            make_float4(accre[nn_][0], accim[nn_][0], accre[nn_][1], accim[nn_][1]);
        reinterpret_cast<float4*>(o)[1] =
            make_float4(accre[nn_][2], accim[nn_][2], accre[nn_][3], accim[nn_][3]);
    }
}

// ---------------------------------------------------------------------------
// Phase 2 (MFMA): one matrix per wave. Algorithm frozen at round-14 state
// (passed, absmax 0.0039); round-17 codegen: v_perm packs, precomputed DS
// base pointers with immediate plane offsets, f32x4 state end-to-end.
// Round-18's two-chain/setprio/peel bundle REGRESSED (VGPR 64->68 crossed
// the occupancy bucket, occ 41->31%) -- reverted to this exact r17 form.
// ---------------------------------------------------------------------------
__global__ __launch_bounds__(256)
void expm_mfma_kernel(const float* __restrict__ dX, const float* __restrict__ Ar,
                      const float* __restrict__ Ai, const float* __restrict__ ws,
                      float* __restrict__ out, const int use_ws, const int real_only)
{
    __shared__ __align__(16) unsigned char ldsraw[WPB * MATB];

    const int t = threadIdx.x;
    const int w = t >> 6;
    const int l = t & 63;
    unsigned char* const L = ldsraw + w * MATB;

    const int m  = blockIdx.x * WPB + w;
    const int n  = m >> 2;
    const int cc = m & 3;

    const int c  = l & 15;         // owned column (C/D); frag row/col
    const int g  = l >> 4;
    const int gh = g & 1;
    const bool gs = (g >= 2);      // k>=16 half -> Y-plane side
    const int colent = c * 48 + gh * 16;
    const int o1 = (gs ? PYH : PXH) + colent;   // B1 / plain-A hi offset
    const int o2 = (gs ? PXH : PYH) + colent;   // B2 hi offset
    const int wc = c * 48 + g * 8;              // colmaj write offset

    // ---- precomputed DS base pointers (all further offsets are imm consts)
    unsigned char* const pWc  = L + RC + wc;                    // colmaj write, RC
    unsigned char* const pWcR = L + RR + wc;                    // colmaj write, RR
    unsigned char* const pWr0 = L + RR + (4 * g) * 48 + c * 2;  // rowmaj scatter base
    const unsigned char* const pRd1 = L + RC + o1;              // B1-style read (RC)
    const unsigned char* const pRd2 = L + RC + o2;              // B2-style read (RC)
    const unsigned char* const pRdA = L + RR + o1;              // plain A-read (RR)

    const short ns = (short)0x8000;
    const bf16x8 negall = {ns, ns, ns, ns, ns, ns, ns, ns};
    const bf16x8 zero8  = {0, 0, 0, 0, 0, 0, 0, 0};
    const bf16x8 mB1 = gs ? negall : zero8;   // B1 = [X ; -Y]
    const bf16x8 mA1 = gs ? zero8 : negall;   // A-op of skew-Herm A: [-X | +Y]
    const f32x4 fz = {0.f, 0.f, 0.f, 0.f};

    f32x4 dqv;
#pragma unroll
    for (int q = 0; q < 4; ++q) dqv[q] = ((4 * g + q) == c) ? 1.f : 0.f;

    // ---- load AX (C/D ownership) + transposed elements; skew-project
    f32x4 aRv, aIv;
    if (use_ws) {
        const float* gp = ws + (size_t)m * 512;
#pragma unroll
        for (int q = 0; q < 4; ++q) {
            const int r = 4 * g + q;
            const float2 v = *reinterpret_cast<const float2*>(gp + (r * 16 + c) * 2);
            const float2 u = *reinterpret_cast<const float2*>(gp + (c * 16 + r) * 2);
            aRv[q] = 0.5f * (v.x - u.x);
            aIv[q] = 0.5f * (v.y + u.y);
        }
    } else {
        float bRe[4] = {0,0,0,0}, bIm[4] = {0,0,0,0}, uRe[4] = {0,0,0,0}, uIm[4] = {0,0,0,0};
        for (int k = 0; k < IN_DIM; ++k) {
            const float dxv = dX[n * IN_DIM + k];
            const int base = (k * CC + cc) * 256;
#pragma unroll
            for (int q = 0; q < 4; ++q) {
                const int r = 4 * g + q;
                bRe[q] = fmaf(dxv, Ar[base + r * 16 + c], bRe[q]);
                bIm[q] = fmaf(dxv, Ai[base + r * 16 + c], bIm[q]);
                uRe[q] = fmaf(dxv, Ar[base + c * 16 + r], uRe[q]);
                uIm[q] = fmaf(dxv, Ai[base + c * 16 + r], uIm[q]);
            }
        }
#pragma unroll
        for (int q = 0; q < 4; ++q) {
            aRv[q] = 0.5f * (bRe[q] - uRe[q]);
            aIv[q] = 0.5f * (bIm[q] + uIm[q]);
        }
    }

    // ---- helpers (all DS via fixed pointers + imm offsets) -------------------
    auto wcolV = [&](unsigned char* Rb, const f32x4 vR, const f32x4 vI) {
        uint2 xh, yh, xl, yl;
        xh.x = pkp(vR[0], vR[1]); xh.y = pkp(vR[2], vR[3]);
        yh.x = pkp(vI[0], vI[1]); yh.y = pkp(vI[2], vI[3]);
        const float r0 = vR[0] - hif(vR[0]), r1 = vR[1] - hif(vR[1]);
        const float r2 = vR[2] - hif(vR[2]), r3 = vR[3] - hif(vR[3]);
        const float i0 = vI[0] - hif(vI[0]), i1 = vI[1] - hif(vI[1]);
        const float i2 = vI[2] - hif(vI[2]), i3 = vI[3] - hif(vI[3]);
        xl.x = pkp(r0, r1); xl.y = pkp(r2, r3);
        yl.x = pkp(i0, i1); yl.y = pkp(i2, i3);
        *reinterpret_cast<uint2*>(Rb + PXH)       = xh;
        *reinterpret_cast<uint2*>(Rb + PYH)       = yh;
        *reinterpret_cast<uint2*>(Rb + PXH + LOD) = xl;
        *reinterpret_cast<uint2*>(Rb + PYH + LOD) = yl;
    };
    auto wrowV = [&](const f32x4 vR, const f32x4 vI) {
#pragma unroll
        for (int q = 0; q < 4; ++q) {
            unsigned char* p = pWr0 + q * 48;
            *reinterpret_cast<unsigned short*>(p + PXH) =
                (unsigned short)(fbits(vR[q]) >> 16);
            *reinterpret_cast<unsigned short*>(p + PYH) =
                (unsigned short)(fbits(vI[q]) >> 16);
            const float lr = vR[q] - hif(vR[q]);
            const float li = vI[q] - hif(vI[q]);
            *reinterpret_cast<unsigned short*>(p + PXH + LOD) =
                (unsigned short)(fbits(lr) >> 16);
            *reinterpret_cast<unsigned short*>(p + PYH + LOD) =
                (unsigned short)(fbits(li) >> 16);
        }
    };
    // acc += (A-frags) * (matrix colmaj in RC): B1/B2 imm-offset reads + 3+3 mfma
    auto cmulV = [&](const bf16x8 Ah, const bf16x8 Al,
                     f32x4& re, f32x4& im, bool doIm) {
        const bf16x8 b1h = *reinterpret_cast<const bf16x8*>(pRd1) ^ mB1;
        const bf16x8 b1l = *reinterpret_cast<const bf16x8*>(pRd1 + LOD) ^ mB1;
        re = MFMA16(Ah, b1h, re);
        re = MFMA16(Ah, b1l, re);
        re = MFMA16(Al, b1h, re);
        if (doIm) {
            const bf16x8 b2h = *reinterpret_cast<const bf16x8*>(pRd2);
            const bf16x8 b2l = *reinterpret_cast<const bf16x8*>(pRd2 + LOD);
            im = MFMA16(Ah, b2h, im);
            im = MFMA16(Ah, b2l, im);
            im = MFMA16(Al, b2h, im);
        }
    };

    // ---- unscaled A -> RC colmaj; Z0 = A*A (A-op = masked read of colmaj(A))
    wcolV(pWc, aRv, aIv);
    {
        const bf16x8 fh = *reinterpret_cast<const bf16x8*>(pRd1) ^ mA1;
        const bf16x8 fl = *reinterpret_cast<const bf16x8*>(pRd1 + LOD) ^ mA1;
        f32x4 zr4 = fz, zi4 = fz;
        cmulV(fh, fl, zr4, zi4, true);

        // ---- spectral s: ||A||_2^2 = ||Z0||_2 <= ||Z0||_1
        float colsum = 0.f;
#pragma unroll
        for (int q = 0; q < 4; ++q)
            colsum += sqrtf(zr4[q] * zr4[q] + zi4[q] * zi4[q]);
        colsum += __shfl_xor(colsum, 16);
        colsum += __shfl_xor(colsum, 32);
        float mx = colsum;
        mx = fmaxf(mx, __shfl_xor(mx, 1));
        mx = fmaxf(mx, __shfl_xor(mx, 2));
        mx = fmaxf(mx, __shfl_xor(mx, 4));
        mx = fmaxf(mx, __shfl_xor(mx, 8));

        int s_ = 0;
        if (mx > 1.f) s_ = (int)ceilf(0.5f * log2f(mx));
        if (s_ < 0) s_ = 0;
        if (s_ > 16) s_ = 16;
        const float sc1 = exp2f((float)(-s_));
        const float sc2 = sc1 * sc1;

        f32x4 zrv, ziv, nzv;
#pragma unroll
        for (int q = 0; q < 4; ++q) {
            aRv[q] *= sc1; aIv[q] *= sc1;
            zrv[q] = zr4[q] * sc2; ziv[q] = zi4[q] * sc2;
            nzv[q] = -ziv[q];
        }

        // ---- conj(Z) colmaj -> RR (== rowmaj(Z)); plain A-read presents Z
        wcolV(pWcR, zrv, nzv);
        const bf16x8 zfh = *reinterpret_cast<const bf16x8*>(pRdA);
        const bf16x8 zfl = *reinterpret_cast<const bf16x8*>(pRdA + LOD);

        // ---- seeds: T = C8 Z + C7 A + C6 I
        f32x4 tRv, tIv;
#pragma unroll
        for (int q = 0; q < 4; ++q) {
            tRv[q] = C8 * zrv[q] + C7 * aRv[q] + C6 * dqv[q];
            tIv[q] = C8 * ziv[q] + C7 * aIv[q];
        }

        // ---- 3 Horner steps: T <- Z*T + (eI + oA)
        const float cE[3] = {C4, C2, C0};
        const float cO[3] = {C5, C3, C1};
#pragma unroll
        for (int h = 0; h < 3; ++h) {
            wcolV(pWc, tRv, tIv);
            f32x4 ar, ai;
#pragma unroll
            for (int q = 0; q < 4; ++q) {
                ar[q] = cO[h] * aRv[q] + cE[h] * dqv[q];
                ai[q] = cO[h] * aIv[q];
            }
            cmulV(zfh, zfl, ar, ai, true);
            tRv = ar; tIv = ai;
        }

        // ---- s squarings: wcol(T)+wrow(T); A-op = plain rowmaj(T) read
#pragma unroll 1
        for (int it = 0; it < s_; ++it) {
            wcolV(pWc, tRv, tIv);
            wrowV(tRv, tIv);
            const bf16x8 afh = *reinterpret_cast<const bf16x8*>(pRdA);
            const bf16x8 afl = *reinterpret_cast<const bf16x8*>(pRdA + LOD);
            const bool needIm = !(real_only && (it == s_ - 1));
            f32x4 r = fz, i4 = fz;
            cmulV(afh, afl, r, i4, needIm);
            tRv = r;
            if (needIm) tIv = i4;
        }

        // ---- write result
        if (real_only) {
            float* po = out + (size_t)m * 256;
#pragma unroll
            for (int q = 0; q < 4; ++q)
                po[(4 * g + q) * 16 + c] = tRv[q];
        } else {
            float* po = out + (size_t)m * 512;
#pragma unroll
            for (int q = 0; q < 4; ++q)
                *reinterpret_cast<float2*>(po + ((4 * g + q) * 16 + c) * 2) =
                    make_float2(tRv[q], tIv[q]);
        }
    }
}

// ---------------------------------------------------------------------------
extern "C" void kernel_launch(void* const* d_in, const int* in_sizes, int n_in,
                              void* d_out, int out_size, void* d_ws, size_t ws_size,
                              hipStream_t stream)
{
    const float* dX = (const float*)d_in[0];
    const float* Ar = (const float*)d_in[1];
    const float* Ai = (const float*)d_in[2];
    float* out = (float*)d_out;
    float* ws  = (float*)d_ws;

    const int real_only = (out_size < NMAT * 512) ? 1 : 0;
    const size_t need = (size_t)NMAT * 512 * sizeof(float);
    const int use_ws = (ws_size >= need) ? 1 : 0;

    if (use_ws)
        hipLaunchKernelGGL(ax_kernel, dim3(NN / 8), dim3(256), 0, stream, dX, Ar, Ai, ws);
    hipLaunchKernelGGL(expm_mfma_kernel, dim3(NMAT / WPB), dim3(256), 0, stream,
                       dX, Ar, Ai, ws, out, use_ws, real_only);
}